// Round 1
// baseline (322.957 us; speedup 1.0000x reference)
//
#include <hip/hip_runtime.h>

// GRUCell fused kernel for MI355X (gfx950).
// B=65536, I=128, H=256, CAT=384.
// Strategy: f16 MFMA (16x16x32) for all three GEMMs; per-block tile = 64 batch
// rows x full 256 hidden so r/z stay block-local; r*h overwrites the h-part of
// the LDS activation tile in place so phase 2 is a single K=384 GEMM.

#define BATCH   65536
#define ISZ     128
#define HSZ     256
#define CAT     384
#define BM      64
#define NTHREADS 512
#define ROWB    768          // bytes per LDS row (384 f16)

using half8  = __attribute__((ext_vector_type(8))) _Float16;
using floatx4 = __attribute__((ext_vector_type(4))) float;

__device__ __forceinline__ float hsig(float x) {
    return fminf(fmaxf(x * (1.0f/6.0f) + 0.5f, 0.0f), 1.0f);
}
__device__ __forceinline__ float htanh(float x) {
    return fminf(fmaxf(x, -1.0f), 1.0f);
}

__device__ __forceinline__ half8 cvt8(float4 v0, float4 v1) {
    half8 h;
    h[0] = (_Float16)v0.x; h[1] = (_Float16)v0.y;
    h[2] = (_Float16)v0.z; h[3] = (_Float16)v0.w;
    h[4] = (_Float16)v1.x; h[5] = (_Float16)v1.y;
    h[6] = (_Float16)v1.z; h[7] = (_Float16)v1.w;
    return h;
}

// ---- weight prep: f32 [256x384] row-major -> f16 same layout in d_ws ----
__global__ __launch_bounds__(256) void prep_weights(
    const float* __restrict__ Wz, const float* __restrict__ Wr,
    const float* __restrict__ Wh, _Float16* __restrict__ ws)
{
    const int m = blockIdx.y;
    const float* src = (m == 0) ? Wz : (m == 1) ? Wr : Wh;
    _Float16* dst = ws + (size_t)m * (HSZ * CAT);
    const int base = (blockIdx.x * 256 + threadIdx.x) * 8;  // 48*256*8 = 98304
    float4 v0 = *(const float4*)(src + base);
    float4 v1 = *(const float4*)(src + base + 4);
    *(half8*)(dst + base) = cvt8(v0, v1);
}

// swizzled LDS byte offset for f16 element k of row r (XOR on bits 4..6)
__device__ __forceinline__ int lds_byte(int row, int kbyte) {
    return row * ROWB + (kbyte ^ ((row & 7) << 4));
}

__global__ __launch_bounds__(NTHREADS) void gru_kernel(
    const float* __restrict__ x, const float* __restrict__ h_prev,
    const float* __restrict__ b_z, const float* __restrict__ b_r,
    const float* __restrict__ b_h, const _Float16* __restrict__ wf,
    float* __restrict__ out)
{
    __shared__ __align__(16) unsigned char lds[BM * ROWB];  // 48 KiB
    const int t    = threadIdx.x;
    const int row0 = blockIdx.x * BM;

    // ---- stage x (64x128 f32 -> f16) ----
    for (int c = t; c < BM * 16; c += NTHREADS) {          // 16 chunks/row
        int row = c >> 4, kc = c & 15;
        const float* g = x + (size_t)(row0 + row) * ISZ + kc * 8;
        float4 v0 = *(const float4*)g;
        float4 v1 = *(const float4*)(g + 4);
        *(half8*)(lds + lds_byte(row, kc * 16)) = cvt8(v0, v1);
    }
    // ---- stage h (64x256 f32 -> f16) at k offset 128 ----
    for (int c = t; c < BM * 32; c += NTHREADS) {          // 32 chunks/row
        int row = c >> 5, kc = c & 31;
        const float* g = h_prev + (size_t)(row0 + row) * HSZ + kc * 8;
        float4 v0 = *(const float4*)g;
        float4 v1 = *(const float4*)(g + 4);
        *(half8*)(lds + lds_byte(row, 256 + kc * 16)) = cvt8(v0, v1);
    }
    __syncthreads();

    const int lane = t & 63;
    const int w    = t >> 6;
    const int mg   = w >> 2;        // 0..1 : rows mg*32 .. +31
    const int ng   = w & 3;         // 0..3 : cols ng*64 .. +63
    const int lr   = lane & 15;     // fragment row/col index
    const int lk   = lane >> 4;     // k-quad (8 f16 each)

    const _Float16* wz = wf;
    const _Float16* wr = wf + HSZ * CAT;
    const _Float16* wh = wf + 2 * HSZ * CAT;

    floatx4 accz[2][4] = {};
    floatx4 accr[2][4] = {};

    // ---- phase 1: Z and R pre-activations, K = 384 ----
    for (int kk = 0; kk < 12; ++kk) {
        const int k0 = kk * 32;
        half8 a[2];
        #pragma unroll
        for (int f = 0; f < 2; ++f) {
            int row = mg * 32 + f * 16 + lr;
            a[f] = *(const half8*)(lds + lds_byte(row, (k0 + lk * 8) * 2));
        }
        #pragma unroll
        for (int j = 0; j < 4; ++j) {
            int n = ng * 64 + j * 16 + lr;
            const int off = n * CAT + k0 + lk * 8;
            half8 bzf = *(const half8*)(wz + off);
            half8 brf = *(const half8*)(wr + off);
            #pragma unroll
            for (int f = 0; f < 2; ++f) {
                accz[f][j] = __builtin_amdgcn_mfma_f32_16x16x32_f16(a[f], bzf, accz[f][j], 0, 0, 0);
                accr[f][j] = __builtin_amdgcn_mfma_f32_16x16x32_f16(a[f], brf, accr[f][j], 0, 0, 0);
            }
        }
    }

    float bzv[4], brv[4];
    #pragma unroll
    for (int j = 0; j < 4; ++j) {
        int col = ng * 64 + j * 16 + lr;
        bzv[j] = b_z[col];
        brv[j] = b_r[col];
    }

    __syncthreads();  // all phase-1 LDS reads complete before overwrite

    // z = hsig(.) kept in regs (accz); r -> r*h_prev overwrites LDS h-region
    #pragma unroll
    for (int f = 0; f < 2; ++f) {
        #pragma unroll
        for (int j = 0; j < 4; ++j) {
            #pragma unroll
            for (int q = 0; q < 4; ++q) {
                int row = mg * 32 + f * 16 + lk * 4 + q;   // C/D: row=(l>>4)*4+q
                int col = ng * 64 + j * 16 + lr;           //      col=l&15
                accz[f][j][q] = hsig(accz[f][j][q] + bzv[j]);
                float rr = hsig(accr[f][j][q] + brv[j]);
                float hv = h_prev[(size_t)(row0 + row) * HSZ + col];
                *(_Float16*)(lds + lds_byte(row, 256 + col * 2)) = (_Float16)(rr * hv);
            }
        }
    }
    __syncthreads();

    // ---- phase 2: h_tilde pre-activation = concat(x, r*h) @ W_h^T, K = 384 ----
    floatx4 acch[2][4] = {};
    for (int kk = 0; kk < 12; ++kk) {
        const int k0 = kk * 32;
        half8 a[2];
        #pragma unroll
        for (int f = 0; f < 2; ++f) {
            int row = mg * 32 + f * 16 + lr;
            a[f] = *(const half8*)(lds + lds_byte(row, (k0 + lk * 8) * 2));
        }
        #pragma unroll
        for (int j = 0; j < 4; ++j) {
            int n = ng * 64 + j * 16 + lr;
            half8 bhf = *(const half8*)(wh + n * CAT + k0 + lk * 8);
            #pragma unroll
            for (int f = 0; f < 2; ++f) {
                acch[f][j] = __builtin_amdgcn_mfma_f32_16x16x32_f16(a[f], bhf, acch[f][j], 0, 0, 0);
            }
        }
    }

    float bhv[4];
    #pragma unroll
    for (int j = 0; j < 4; ++j) bhv[j] = b_h[ng * 64 + j * 16 + lr];

    // ---- epilogue: h_next = z*h + (1-z)*hardtanh(.) ----
    #pragma unroll
    for (int f = 0; f < 2; ++f) {
        #pragma unroll
        for (int j = 0; j < 4; ++j) {
            #pragma unroll
            for (int q = 0; q < 4; ++q) {
                int row = mg * 32 + f * 16 + lk * 4 + q;
                int col = ng * 64 + j * 16 + lr;
                float ht = htanh(acch[f][j][q] + bhv[j]);
                float zz = accz[f][j][q];
                float hv = h_prev[(size_t)(row0 + row) * HSZ + col];
                out[(size_t)(row0 + row) * HSZ + col] = zz * hv + (1.0f - zz) * ht;
            }
        }
    }
}

extern "C" void kernel_launch(void* const* d_in, const int* in_sizes, int n_in,
                              void* d_out, int out_size, void* d_ws, size_t ws_size,
                              hipStream_t stream) {
    const float* x  = (const float*)d_in[0];
    const float* h  = (const float*)d_in[1];
    const float* Wz = (const float*)d_in[2];
    const float* bz = (const float*)d_in[3];
    const float* Wr = (const float*)d_in[4];
    const float* br = (const float*)d_in[5];
    const float* Wh = (const float*)d_in[6];
    const float* bh = (const float*)d_in[7];
    _Float16* wf = (_Float16*)d_ws;   // 3*256*384*2 = 576 KiB of scratch

    prep_weights<<<dim3(48, 3), 256, 0, stream>>>(Wz, Wr, Wh, wf);
    gru_kernel<<<dim3(BATCH / BM), NTHREADS, 0, stream>>>(
        x, h, bz, br, bh, wf, (float*)d_out);
}

// Round 2
// 206.618 us; speedup vs baseline: 1.5631x; 1.5631x over previous
//
#include <hip/hip_runtime.h>

// GRUCell fused kernel for MI355X (gfx950), round 2.
// B=65536, I=128, H=256, CAT=384. f16 MFMA 16x16x32.
// R1 -> R2: weights now stream through LDS via global_load_lds (fire-and-forget,
// swizzled-source / swizzled-read per guide rule 21); reg budget capped at 128
// (launch_bounds(512,4)) so 2 blocks/CU co-reside and cover chunk-load latency.

#define BATCH   65536
#define ISZ     128
#define HSZ     256
#define CAT     384
#define BM      64
#define NT      512
#define ROWB    768            // act row bytes (384 f16)
#define ACT_B   (BM * ROWB)    // 49152
#define WBUF_B  32768          // 512 rows x 64 B (32 f16 per row)

using half8   = __attribute__((ext_vector_type(8))) _Float16;
using floatx4 = __attribute__((ext_vector_type(4))) float;

#define WAITV asm volatile("s_waitcnt vmcnt(0)" ::: "memory")

typedef unsigned int u32;
typedef __attribute__((address_space(1))) const u32 gu32;
typedef __attribute__((address_space(3))) u32 lu32;

__device__ __forceinline__ void gload16(const void* g, void* l) {
    __builtin_amdgcn_global_load_lds((gu32*)g, (lu32*)l, 16, 0, 0);
}

__device__ __forceinline__ float hsig(float x) {
    return fminf(fmaxf(x * (1.0f / 6.0f) + 0.5f, 0.0f), 1.0f);
}
__device__ __forceinline__ float htanh(float x) {
    return fminf(fmaxf(x, -1.0f), 1.0f);
}
__device__ __forceinline__ half8 cvt8(float4 v0, float4 v1) {
    half8 h;
    h[0] = (_Float16)v0.x; h[1] = (_Float16)v0.y;
    h[2] = (_Float16)v0.z; h[3] = (_Float16)v0.w;
    h[4] = (_Float16)v1.x; h[5] = (_Float16)v1.y;
    h[6] = (_Float16)v1.z; h[7] = (_Float16)v1.w;
    return h;
}

// ---- weight prep: f32 [256x384] row-major -> f16 same layout in d_ws ----
// layout in ws: Wz rows 0..255, Wr rows 256..511, Wh rows 512..767 (contiguous)
__global__ __launch_bounds__(256) void prep_weights(
    const float* __restrict__ Wz, const float* __restrict__ Wr,
    const float* __restrict__ Wh, _Float16* __restrict__ ws)
{
    const int m = blockIdx.y;
    const float* src = (m == 0) ? Wz : (m == 1) ? Wr : Wh;
    _Float16* dst = ws + (size_t)m * (HSZ * CAT);
    const int base = (blockIdx.x * 256 + threadIdx.x) * 8;
    float4 v0 = *(const float4*)(src + base);
    float4 v1 = *(const float4*)(src + base + 4);
    *(half8*)(dst + base) = cvt8(v0, v1);
}

// Issue one weight K-chunk (32 f16 per row) into wbuf via global_load_lds.
// wbuf row n (64B) holds W[n][kk*32 .. +31]; 16B slot s holds source slot
// s ^ ((n>>1)&3)  (XOR swizzle -> conflict-free swizzled ds_read later).
// One wave-load i covers rows i*16..i*16+15 (lane: n = i*16 + (lane>>2),
// phys slot = lane&3). nper wave-loads per wave.
__device__ __forceinline__ void issue_w(const _Float16* __restrict__ wsrc,
                                        unsigned char* wdst, int w, int lane,
                                        int kk, int nper) {
    #pragma unroll
    for (int ii = 0; ii < nper; ++ii) {
        const int i = w * nper + ii;
        const int n = i * 16 + (lane >> 2);
        const int sslot = (lane & 3) ^ ((n >> 1) & 3);
        gload16(wsrc + n * CAT + kk * 32 + sslot * 8, wdst + i * 1024);
    }
}

// swizzled read of the 16B B-fragment for weight row n, k-slot lk
__device__ __forceinline__ half8 wread(const unsigned char* wbuf, int n, int lk) {
    return *(const half8*)(wbuf + n * 64 + ((lk ^ ((n >> 1) & 3)) << 4));
}

__global__ __launch_bounds__(NT, 4) void gru_kernel(
    const float* __restrict__ x, const float* __restrict__ h_prev,
    const float* __restrict__ b_z, const float* __restrict__ b_r,
    const float* __restrict__ b_h, const _Float16* __restrict__ wf,
    float* __restrict__ out)
{
    __shared__ __align__(16) unsigned char lds[ACT_B + WBUF_B];  // 80 KiB
    unsigned char* const act  = lds;
    unsigned char* const wbuf = lds + ACT_B;

    const int t    = threadIdx.x;
    const int lane = t & 63;
    const int w    = t >> 6;
    const int mg   = w >> 2;       // row group: rows mg*32 .. +31
    const int ng   = w & 3;        // col group: cols ng*64 .. +63
    const int lr   = lane & 15;
    const int lk   = lane >> 4;
    const int row0 = blockIdx.x * BM;
    const _Float16* wh = wf + 2 * HSZ * CAT;

    // kick off phase-1 weight chunk 0 (latency hides under act staging)
    issue_w(wf, wbuf, w, lane, 0, 4);

    // ---- stage x (64x128) and h (64x256), f32 -> f16, swizzled ----
    for (int c = t; c < BM * 16; c += NT) {
        int row = c >> 4, kc = c & 15;
        const float* g = x + (size_t)(row0 + row) * ISZ + kc * 8;
        float4 v0 = *(const float4*)g;
        float4 v1 = *(const float4*)(g + 4);
        *(half8*)(act + row * ROWB + ((kc * 16) ^ ((row & 7) << 4))) = cvt8(v0, v1);
    }
    for (int c = t; c < BM * 32; c += NT) {
        int row = c >> 5, kc = c & 31;
        const float* g = h_prev + (size_t)(row0 + row) * HSZ + kc * 8;
        float4 v0 = *(const float4*)g;
        float4 v1 = *(const float4*)(g + 4);
        *(half8*)(act + row * ROWB + ((256 + kc * 16) ^ ((row & 7) << 4))) = cvt8(v0, v1);
    }
    WAITV;
    __syncthreads();   // act + weight chunk 0 ready

    floatx4 accz[2][4] = {};
    floatx4 accr[2][4] = {};
    const int rowA = mg * 32 + lr;
    const int asw  = (rowA & 7) << 4;

    // ---- phase 1: z,r pre-activations, K-chunks of 32 ----
    #pragma unroll 1
    for (int kk = 0; kk < 12; ++kk) {
        half8 a0 = *(const half8*)(act + rowA * ROWB        + ((kk * 64 + lk * 16) ^ asw));
        half8 a1 = *(const half8*)(act + (rowA + 16) * ROWB + ((kk * 64 + lk * 16) ^ asw));
        half8 bf[4];
        #pragma unroll
        for (int j = 0; j < 4; ++j) bf[j] = wread(wbuf, ng * 64 + j * 16 + lr, lk);
        #pragma unroll
        for (int j = 0; j < 4; ++j) {
            accz[0][j] = __builtin_amdgcn_mfma_f32_16x16x32_f16(a0, bf[j], accz[0][j], 0, 0, 0);
            accz[1][j] = __builtin_amdgcn_mfma_f32_16x16x32_f16(a1, bf[j], accz[1][j], 0, 0, 0);
        }
        #pragma unroll
        for (int j = 0; j < 4; ++j) bf[j] = wread(wbuf, 256 + ng * 64 + j * 16 + lr, lk);
        #pragma unroll
        for (int j = 0; j < 4; ++j) {
            accr[0][j] = __builtin_amdgcn_mfma_f32_16x16x32_f16(a0, bf[j], accr[0][j], 0, 0, 0);
            accr[1][j] = __builtin_amdgcn_mfma_f32_16x16x32_f16(a1, bf[j], accr[1][j], 0, 0, 0);
        }
        __syncthreads();                       // all waves done reading wbuf
        if (kk < 11) {
            issue_w(wf, wbuf, w, lane, kk + 1, 4);
            WAITV;
            __syncthreads();                   // next chunk resident
        }
    }

    // wbuf free: start phase-2 chunk 0 (Wh, 256 rows -> 16KB, 2 loads/wave)
    issue_w(wh, wbuf, w, lane, 0, 2);

    // ---- z = hsig(.), r -> r*h overwrites act h-region (overlaps load) ----
    float bzv[4], brv[4];
    #pragma unroll
    for (int j = 0; j < 4; ++j) {
        int col = ng * 64 + j * 16 + lr;
        bzv[j] = b_z[col];
        brv[j] = b_r[col];
    }
    #pragma unroll
    for (int f = 0; f < 2; ++f) {
        #pragma unroll
        for (int j = 0; j < 4; ++j) {
            #pragma unroll
            for (int q = 0; q < 4; ++q) {
                int row = mg * 32 + f * 16 + lk * 4 + q;   // C/D: row=(l>>4)*4+q
                int col = ng * 64 + j * 16 + lr;           //      col=l&15
                accz[f][j][q] = hsig(accz[f][j][q] + bzv[j]);
                float rr = hsig(accr[f][j][q] + brv[j]);
                _Float16* hp = (_Float16*)(act + row * ROWB +
                                           ((256 + col * 2) ^ ((row & 7) << 4)));
                float hv = (float)hp[0];
                hp[0] = (_Float16)(rr * hv);
            }
        }
    }
    WAITV;
    __syncthreads();   // rh visible to all; Wh chunk 0 resident

    // ---- phase 2: h_tilde pre-activation ----
    floatx4 acch[2][4] = {};
    #pragma unroll 1
    for (int kk = 0; kk < 12; ++kk) {
        half8 a0 = *(const half8*)(act + rowA * ROWB        + ((kk * 64 + lk * 16) ^ asw));
        half8 a1 = *(const half8*)(act + (rowA + 16) * ROWB + ((kk * 64 + lk * 16) ^ asw));
        half8 bf[4];
        #pragma unroll
        for (int j = 0; j < 4; ++j) bf[j] = wread(wbuf, ng * 64 + j * 16 + lr, lk);
        #pragma unroll
        for (int j = 0; j < 4; ++j) {
            acch[0][j] = __builtin_amdgcn_mfma_f32_16x16x32_f16(a0, bf[j], acch[0][j], 0, 0, 0);
            acch[1][j] = __builtin_amdgcn_mfma_f32_16x16x32_f16(a1, bf[j], acch[1][j], 0, 0, 0);
        }
        if (kk < 11) {
            __syncthreads();
            issue_w(wh, wbuf, w, lane, kk + 1, 2);
            WAITV;
            __syncthreads();
        }
    }

    // ---- epilogue: h_next = z*h + (1-z)*hardtanh(.) ----
    float bhv[4];
    #pragma unroll
    for (int j = 0; j < 4; ++j) bhv[j] = b_h[ng * 64 + j * 16 + lr];
    #pragma unroll
    for (int f = 0; f < 2; ++f) {
        #pragma unroll
        for (int j = 0; j < 4; ++j) {
            #pragma unroll
            for (int q = 0; q < 4; ++q) {
                int row = mg * 32 + f * 16 + lk * 4 + q;
                int col = ng * 64 + j * 16 + lr;
                float ht = htanh(acch[f][j][q] + bhv[j]);
                float zz = accz[f][j][q];
                float hv = h_prev[(size_t)(row0 + row) * HSZ + col];
                out[(size_t)(row0 + row) * HSZ + col] = zz * hv + (1.0f - zz) * ht;
            }
        }
    }
}

extern "C" void kernel_launch(void* const* d_in, const int* in_sizes, int n_in,
                              void* d_out, int out_size, void* d_ws, size_t ws_size,
                              hipStream_t stream) {
    const float* x  = (const float*)d_in[0];
    const float* h  = (const float*)d_in[1];
    const float* Wz = (const float*)d_in[2];
    const float* bz = (const float*)d_in[3];
    const float* Wr = (const float*)d_in[4];
    const float* br = (const float*)d_in[5];
    const float* Wh = (const float*)d_in[6];
    const float* bh = (const float*)d_in[7];
    _Float16* wf = (_Float16*)d_ws;   // 3*256*384*2 = 576 KiB scratch

    prep_weights<<<dim3(48, 3), 256, 0, stream>>>(Wz, Wr, Wh, wf);
    gru_kernel<<<dim3(BATCH / BM), NT, 0, stream>>>(
        x, h, bz, br, bh, wf, (float*)d_out);
}

// Round 4
// 198.459 us; speedup vs baseline: 1.6273x; 1.0411x over previous
//
#include <hip/hip_runtime.h>

// GRUCell fused kernel for MI355X (gfx950), round 4.
// B=65536, I=128, H=256, CAT=384. f16 MFMA 16x16x32.
// R3 -> R4: fix phase-2 tail — final h-chunk (kk=11) has no younger loads
// behind it, so vmcnt(2) passed without waiting and the last K-slice read a
// not-yet-landed buffer. Final iteration now drains vmcnt(0). Rest unchanged:
// counted-vmcnt double-buffered weight pipeline, raw s_barrier, z/r chunk
// alternation keeps one chunk in flight during the other matrix's MFMA.

#define BATCH 65536
#define ISZ   128
#define HSZ   256
#define CAT   384
#define BM    64
#define NT    512
#define ROWB  768              // act row bytes (384 f16)
#define ACT_B (BM * ROWB)      // 49152
#define CH_B  16384            // one weight chunk: 256 rows x 64 B (K=32)

using half8   = __attribute__((ext_vector_type(8))) _Float16;
using floatx4 = __attribute__((ext_vector_type(4))) float;

typedef unsigned int u32;
typedef __attribute__((address_space(1))) const u32 gu32;
typedef __attribute__((address_space(3))) u32 lu32;

__device__ __forceinline__ void gload16(const void* g, void* l) {
    __builtin_amdgcn_global_load_lds((gu32*)g, (lu32*)l, 16, 0, 0);
}

#define BAR()      __builtin_amdgcn_s_barrier()
#define SCHED0()   __builtin_amdgcn_sched_barrier(0)
#define WAIT_VM2() asm volatile("s_waitcnt vmcnt(2)" ::: "memory")
#define WAIT_VM0() asm volatile("s_waitcnt vmcnt(0)" ::: "memory")
#define WAIT_LG0() asm volatile("s_waitcnt lgkmcnt(0)" ::: "memory")
#define MFMA       __builtin_amdgcn_mfma_f32_16x16x32_f16

__device__ __forceinline__ float hsig(float x) {
    return fminf(fmaxf(x * (1.0f / 6.0f) + 0.5f, 0.0f), 1.0f);
}
__device__ __forceinline__ float htanh(float x) {
    return fminf(fmaxf(x, -1.0f), 1.0f);
}
__device__ __forceinline__ half8 cvt8(float4 v0, float4 v1) {
    half8 h;
    h[0] = (_Float16)v0.x; h[1] = (_Float16)v0.y;
    h[2] = (_Float16)v0.z; h[3] = (_Float16)v0.w;
    h[4] = (_Float16)v1.x; h[5] = (_Float16)v1.y;
    h[6] = (_Float16)v1.z; h[7] = (_Float16)v1.w;
    return h;
}

// ---- weight prep: f32 [256x384] row-major -> f16 same layout in d_ws ----
// ws layout: Wz rows 0..255, Wr 256..511, Wh 512..767
__global__ __launch_bounds__(256) void prep_weights(
    const float* __restrict__ Wz, const float* __restrict__ Wr,
    const float* __restrict__ Wh, _Float16* __restrict__ ws)
{
    const int m = blockIdx.y;
    const float* src = (m == 0) ? Wz : (m == 1) ? Wr : Wh;
    _Float16* dst = ws + (size_t)m * (HSZ * CAT);
    const int base = (blockIdx.x * 256 + threadIdx.x) * 8;
    float4 v0 = *(const float4*)(src + base);
    float4 v1 = *(const float4*)(src + base + 4);
    *(half8*)(dst + base) = cvt8(v0, v1);
}

// chunk c: c<24 -> matrix (c&1 ? Wr : Wz), k-slice c>>1 ; c>=24 -> Wh, slice c-24.
// wbuf row n (64B): phys 16B slot p holds logical slot p ^ ((n>>1)&3).
// global_load_lds dest is wave-uniform base + lane*16: wave-load i covers rows
// i*16 + (lane>>2), phys slot lane&3; source fetches the swizzled logical slot.
__device__ __forceinline__ void issue_chunk(const _Float16* __restrict__ wf,
                                            unsigned char* wbuf, int c,
                                            int w, int lane) {
    const _Float16* src = (c < 24) ? (wf + (c & 1) * (HSZ * CAT))
                                   : (wf + 2 * (HSZ * CAT));
    const int kk = (c < 24) ? (c >> 1) : (c - 24);
    unsigned char* dst = wbuf + (c & 1) * CH_B;
    #pragma unroll
    for (int ii = 0; ii < 2; ++ii) {
        const int i = w * 2 + ii;                  // wave-load 0..15
        const int n = i * 16 + (lane >> 2);        // weight row 0..255
        const int ss = (lane & 3) ^ ((n >> 1) & 3);
        gload16(src + n * CAT + kk * 32 + ss * 8, dst + i * 1024);
    }
}

// swizzled read of the 16B B-fragment for weight row n, k-slot lk
__device__ __forceinline__ half8 wread(const unsigned char* buf, int n, int lk) {
    return *(const half8*)(buf + n * 64 + ((lk ^ ((n >> 1) & 3)) << 4));
}

__global__ __launch_bounds__(NT, 4) void gru_kernel(
    const float* __restrict__ x, const float* __restrict__ h_prev,
    const float* __restrict__ b_z, const float* __restrict__ b_r,
    const float* __restrict__ b_h, const _Float16* __restrict__ wf,
    float* __restrict__ out)
{
    __shared__ __align__(16) unsigned char lds[ACT_B + 2 * CH_B];  // 80 KiB
    unsigned char* const act  = lds;
    unsigned char* const wbuf = lds + ACT_B;

    const int t    = threadIdx.x;
    const int lane = t & 63;
    const int w    = t >> 6;
    const int mg   = w >> 2;        // rows mg*32 .. +31
    const int ng   = w & 3;         // cols ng*64 .. +63
    const int lr   = lane & 15;
    const int lk   = lane >> 4;
    const int row0 = blockIdx.x * BM;

    // prefetch first two weight chunks (z0 -> buf0, r0 -> buf1)
    issue_chunk(wf, wbuf, 0, w, lane);
    issue_chunk(wf, wbuf, 1, w, lane);

    // biases: fold b_z/b_r into accumulator init; b_h held for phase 2
    float bhv[4];
    floatx4 accz[2][4], accr[2][4];
    #pragma unroll
    for (int j = 0; j < 4; ++j) {
        const int col = ng * 64 + j * 16 + lr;
        const float vz = b_z[col];
        const float vr = b_r[col];
        bhv[j] = b_h[col];
        floatx4 tz = {vz, vz, vz, vz};
        floatx4 tr = {vr, vr, vr, vr};
        accz[0][j] = tz; accz[1][j] = tz;
        accr[0][j] = tr; accr[1][j] = tr;
    }

    // ---- stage act: x (64x128) + h (64x256), f32 -> f16, row-XOR swizzled ----
    for (int c = t; c < BM * 16; c += NT) {
        int row = c >> 4, kc = c & 15;
        const float* g = x + (size_t)(row0 + row) * ISZ + kc * 8;
        float4 v0 = *(const float4*)g;
        float4 v1 = *(const float4*)(g + 4);
        *(half8*)(act + row * ROWB + ((kc * 16) ^ ((row & 7) << 4))) = cvt8(v0, v1);
    }
    for (int c = t; c < BM * 32; c += NT) {
        int row = c >> 5, kc = c & 31;
        const float* g = h_prev + (size_t)(row0 + row) * HSZ + kc * 8;
        float4 v0 = *(const float4*)g;
        float4 v1 = *(const float4*)(g + 4);
        *(half8*)(act + row * ROWB + ((256 + kc * 16) ^ ((row & 7) << 4))) = cvt8(v0, v1);
    }
    WAIT_VM0(); WAIT_LG0(); SCHED0();
    BAR();   // act + chunks 0,1 resident for all waves

    const int rowA = mg * 32 + lr;
    const int asw  = (rowA & 7) << 4;     // (rowA+16)&7 == rowA&7

    half8 a0, a1;

    // ---- phase 1: z,r pre-activations; per k: z-chunk (buf0), r-chunk (buf1)
    // Ledger invariant (loads are 2 per chunk, per wave): at each sub-chunk
    // top there are 4 outstanding loads; vmcnt(2) retires exactly the chunk
    // about to be consumed while the next chunk's loads stay in flight.
    #pragma unroll 1
    for (int kk = 0; kk < 12; ++kk) {
        // --- z sub-chunk ---
        WAIT_VM2(); SCHED0(); BAR();
        a0 = *(const half8*)(act + rowA * ROWB        + ((kk * 64 + lk * 16) ^ asw));
        a1 = *(const half8*)(act + (rowA + 16) * ROWB + ((kk * 64 + lk * 16) ^ asw));
        __builtin_amdgcn_s_setprio(1);
        #pragma unroll
        for (int j = 0; j < 4; ++j) {
            half8 bf = wread(wbuf, ng * 64 + j * 16 + lr, lk);
            accz[0][j] = MFMA(a0, bf, accz[0][j], 0, 0, 0);
            accz[1][j] = MFMA(a1, bf, accz[1][j], 0, 0, 0);
        }
        __builtin_amdgcn_s_setprio(0);
        WAIT_LG0(); SCHED0(); BAR();
        issue_chunk(wf, wbuf, 2 * kk + 2, w, lane);   // z_{kk+1} (or h0 at kk=11)
        // --- r sub-chunk (A-frags reused) ---
        WAIT_VM2(); SCHED0(); BAR();
        __builtin_amdgcn_s_setprio(1);
        #pragma unroll
        for (int j = 0; j < 4; ++j) {
            half8 bf = wread(wbuf + CH_B, ng * 64 + j * 16 + lr, lk);
            accr[0][j] = MFMA(a0, bf, accr[0][j], 0, 0, 0);
            accr[1][j] = MFMA(a1, bf, accr[1][j], 0, 0, 0);
        }
        __builtin_amdgcn_s_setprio(0);
        WAIT_LG0(); SCHED0(); BAR();
        issue_chunk(wf, wbuf, 2 * kk + 3, w, lane);   // r_{kk+1} (or h1 at kk=11)
    }

    // ---- rescale: z = hsig(acc), r*h overwrites act h-region in place ----
    // (h0,h1 weight loads are in flight during this window)
    #pragma unroll
    for (int f = 0; f < 2; ++f) {
        #pragma unroll
        for (int j = 0; j < 4; ++j) {
            #pragma unroll
            for (int q = 0; q < 4; ++q) {
                const int row = mg * 32 + f * 16 + lk * 4 + q;  // C/D row=(l>>4)*4+q
                const int col = ng * 64 + j * 16 + lr;          //     col=l&15
                accz[f][j][q] = hsig(accz[f][j][q]);            // bias pre-added
                float rr = hsig(accr[f][j][q]);
                _Float16* hp = (_Float16*)(act + row * ROWB +
                                           ((256 + col * 2) ^ ((row & 7) << 4)));
                float hv = (float)hp[0];
                hp[0] = (_Float16)(rr * hv);
            }
        }
    }
    WAIT_LG0();   // own rescale writes landed; next barrier publishes to all

    // ---- phase 2: h_tilde pre-activation, chunks 24..35 in alternating bufs
    floatx4 acch[2][4];
    #pragma unroll
    for (int j = 0; j < 4; ++j) {
        floatx4 th = {bhv[j], bhv[j], bhv[j], bhv[j]};
        acch[0][j] = th; acch[1][j] = th;
    }
    #pragma unroll 1
    for (int kk = 0; kk < 12; ++kk) {
        // Tail fix (R4): at kk=11 the only outstanding loads ARE chunk 35
        // (h11) — vmcnt(2) would pass without waiting. Drain fully instead.
        if (kk < 11) { WAIT_VM2(); } else { WAIT_VM0(); }
        SCHED0(); BAR();
        const unsigned char* buf = wbuf + (kk & 1) * CH_B;
        a0 = *(const half8*)(act + rowA * ROWB        + ((kk * 64 + lk * 16) ^ asw));
        a1 = *(const half8*)(act + (rowA + 16) * ROWB + ((kk * 64 + lk * 16) ^ asw));
        __builtin_amdgcn_s_setprio(1);
        #pragma unroll
        for (int j = 0; j < 4; ++j) {
            half8 bf = wread(buf, ng * 64 + j * 16 + lr, lk);
            acch[0][j] = MFMA(a0, bf, acch[0][j], 0, 0, 0);
            acch[1][j] = MFMA(a1, bf, acch[1][j], 0, 0, 0);
        }
        __builtin_amdgcn_s_setprio(0);
        WAIT_LG0(); SCHED0(); BAR();
        if (kk < 10) issue_chunk(wf, wbuf, 26 + kk, w, lane);
    }

    // ---- epilogue: h_next = z*h + (1-z)*hardtanh(.) ----
    #pragma unroll
    for (int f = 0; f < 2; ++f) {
        #pragma unroll
        for (int j = 0; j < 4; ++j) {
            #pragma unroll
            for (int q = 0; q < 4; ++q) {
                const int row = mg * 32 + f * 16 + lk * 4 + q;
                const int col = ng * 64 + j * 16 + lr;
                float ht = htanh(acch[f][j][q]);               // bias pre-added
                float zz = accz[f][j][q];
                float hv = h_prev[(size_t)(row0 + row) * HSZ + col];
                out[(size_t)(row0 + row) * HSZ + col] = zz * hv + (1.0f - zz) * ht;
            }
        }
    }
}

extern "C" void kernel_launch(void* const* d_in, const int* in_sizes, int n_in,
                              void* d_out, int out_size, void* d_ws, size_t ws_size,
                              hipStream_t stream) {
    const float* x  = (const float*)d_in[0];
    const float* h  = (const float*)d_in[1];
    const float* Wz = (const float*)d_in[2];
    const float* bz = (const float*)d_in[3];
    const float* Wr = (const float*)d_in[4];
    const float* br = (const float*)d_in[5];
    const float* Wh = (const float*)d_in[6];
    const float* bh = (const float*)d_in[7];
    _Float16* wf = (_Float16*)d_ws;   // 3*256*384*2 = 576 KiB scratch

    prep_weights<<<dim3(48, 3), 256, 0, stream>>>(Wz, Wr, Wh, wf);
    gru_kernel<<<dim3(BATCH / BM), NT, 0, stream>>>(
        x, h, bz, br, bh, wf, (float*)d_out);
}